// Round 1
// baseline (453.627 us; speedup 1.0000x reference)
//
#include <hip/hip_runtime.h>
#include <hip/hip_bf16.h>
#include <stdint.h>

#define Bdim 64
#define Sdim 512
#define Hdim 768
#define G3   2304

typedef float f32x4 __attribute__((ext_vector_type(4)));
typedef short s16x8 __attribute__((ext_vector_type(8)));
typedef short s16x4 __attribute__((ext_vector_type(4)));

__device__ __forceinline__ float bf2f(unsigned short u){
  union { unsigned int i; float f; } c; c.i = ((unsigned int)u) << 16; return c.f;
}
__device__ __forceinline__ unsigned short f2bf(float f){
  union { float f; unsigned int i; } c; c.f = f;
  unsigned int x = c.i;
  return (unsigned short)((x + 0x7fffu + ((x >> 16) & 1u)) >> 16);
}
__device__ __forceinline__ float fast_tanh(float x){
  float e = __expf(2.f * x);
  return 1.f - 2.f / (e + 1.f);
}
__device__ __forceinline__ float fast_sigmoid(float x){
  return 1.f / (1.f + __expf(-x));
}

// ---------------- conversions / transposes ----------------

__global__ __launch_bounds__(256) void k_conv_bf16(const float* __restrict__ src,
                                                   unsigned short* __restrict__ dst, int n8){
  int i = blockIdx.x * 256 + threadIdx.x;
  if (i >= n8) return;
  const float4* s = (const float4*)src;
  float4 a = s[2*i], b = s[2*i+1];
  uint4 o;
  o.x = (unsigned)f2bf(a.x) | ((unsigned)f2bf(a.y) << 16);
  o.y = (unsigned)f2bf(a.z) | ((unsigned)f2bf(a.w) << 16);
  o.z = (unsigned)f2bf(b.x) | ((unsigned)f2bf(b.y) << 16);
  o.w = (unsigned)f2bf(b.z) | ((unsigned)f2bf(b.w) << 16);
  ((uint4*)dst)[i] = o;
}

// ws[768][768] f32 -> wsbT[n][k] bf16 (transposed)
__global__ __launch_bounds__(256) void k_transpose_ws(const float* __restrict__ src,
                                                      unsigned short* __restrict__ dst){
  __shared__ float tile[32][33];
  int bx = blockIdx.x * 32, by = blockIdx.y * 32;
  int tx = threadIdx.x % 32, ty = threadIdx.x / 32;
  for (int j = ty; j < 32; j += 8) tile[j][tx] = src[(size_t)(by + j) * Hdim + bx + tx];
  __syncthreads();
  for (int j = ty; j < 32; j += 8) dst[(size_t)(bx + j) * Hdim + by + tx] = f2bf(tile[tx][j]);
}

// generic f32 transpose: src[R][C] -> dst[C][R]
__global__ __launch_bounds__(256) void k_transpose_f32(const float* __restrict__ src,
                                                       float* __restrict__ dst, int R, int C){
  __shared__ float tile[32][33];
  int bx = blockIdx.x * 32, by = blockIdx.y * 32;
  int tx = threadIdx.x % 32, ty = threadIdx.x / 32;
  for (int j = ty; j < 32; j += 8) tile[j][tx] = src[(size_t)(by + j) * C + bx + tx];
  __syncthreads();
  for (int j = ty; j < 32; j += 8) dst[(size_t)(bx + j) * R + by + tx] = tile[tx][j];
}

// ---------------- Se = SEb @ ws (bf16 MFMA) ----------------
// A: SEb[32768][768] bf16 ; Bt: wsbT[n][k] bf16 ; C: Seb[32768][768] bf16
__global__ __launch_bounds__(256) void k_gemm_se(const unsigned short* __restrict__ A,
                                                 const unsigned short* __restrict__ Bt,
                                                 unsigned short* __restrict__ C){
  __shared__ unsigned short As[128 * 64];
  __shared__ unsigned short Bs[128 * 64];
  const int t = threadIdx.x;
  const int lane = t & 63;
  const int w = t >> 6, wr = w >> 1, wc = w & 1;
  const int m0 = blockIdx.y * 128, n0 = blockIdx.x * 128;

  f32x4 acc[4][4];
  #pragma unroll
  for (int m = 0; m < 4; m++)
    #pragma unroll
    for (int n = 0; n < 4; n++) acc[m][n] = (f32x4){0.f, 0.f, 0.f, 0.f};

  for (int k0 = 0; k0 < Hdim; k0 += 64) {
    // stage 128x64 bf16 tiles, XOR-swizzled LDS (byte ^= (row&7)<<4)
    #pragma unroll
    for (int i = 0; i < 4; i++) {
      int L = t * 16 + i * 4096;
      int row = L >> 7;
      int off = L & 127;
      int soff = off ^ ((row & 7) << 4);
      uint4 va = *(const uint4*)((const char*)A  + ((size_t)(m0 + row) * Hdim + k0) * 2 + off);
      uint4 vb = *(const uint4*)((const char*)Bt + ((size_t)(n0 + row) * Hdim + k0) * 2 + off);
      *(uint4*)((char*)As + row * 128 + soff) = va;
      *(uint4*)((char*)Bs + row * 128 + soff) = vb;
    }
    __syncthreads();
    #pragma unroll
    for (int kk = 0; kk < 2; kk++) {
      s16x8 af[4], bfr[4];
      #pragma unroll
      for (int m = 0; m < 4; m++) {
        int row = wr * 64 + m * 16 + (lane & 15);
        int sw = (row & 7) << 4;
        int kb = kk * 64 + (lane >> 4) * 8;
        s16x4 lo = *(const s16x4*)((const char*)As + row * 128 + (kb ^ sw));
        s16x4 hi = *(const s16x4*)((const char*)As + row * 128 + ((kb + 32) ^ sw));
        af[m] = __builtin_shufflevector(lo, hi, 0, 1, 2, 3, 4, 5, 6, 7);
      }
      #pragma unroll
      for (int n = 0; n < 4; n++) {
        int row = wc * 64 + n * 16 + (lane & 15);
        int sw = (row & 7) << 4;
        int kb = kk * 64 + (lane >> 4) * 8;
        s16x4 lo = *(const s16x4*)((const char*)Bs + row * 128 + (kb ^ sw));
        s16x4 hi = *(const s16x4*)((const char*)Bs + row * 128 + ((kb + 32) ^ sw));
        bfr[n] = __builtin_shufflevector(lo, hi, 0, 1, 2, 3, 4, 5, 6, 7);
      }
      #pragma unroll
      for (int m = 0; m < 4; m++)
        #pragma unroll
        for (int n = 0; n < 4; n++)
          acc[m][n] = __builtin_amdgcn_mfma_f32_16x16x32_bf16(af[m], bfr[n], acc[m][n], 0, 0, 0);
    }
    __syncthreads();
  }
  // epilogue: D row = (lane>>4)*4 + r, col = lane&15
  #pragma unroll
  for (int m = 0; m < 4; m++) {
    int rowb = m0 + wr * 64 + m * 16 + (lane >> 4) * 4;
    #pragma unroll
    for (int n = 0; n < 4; n++) {
      int col = n0 + wc * 64 + n * 16 + (lane & 15);
      #pragma unroll
      for (int r = 0; r < 4; r++)
        C[(size_t)(rowb + r) * Hdim + col] = f2bf(acc[m][n][r]);
    }
  }
}

// ---------------- small row-GEMM: C[64][768] = X1@W1 (+ X2@W2) ----------------
__global__ __launch_bounds__(128) void k_vecmat(const float* __restrict__ X1, const float* __restrict__ W1,
                                                const float* __restrict__ X2, const float* __restrict__ W2,
                                                float* __restrict__ Cout){
  __shared__ float x1[Hdim], x2[Hdim];
  int b = blockIdx.y;
  int c = blockIdx.x * 128 + threadIdx.x;
  bool dual = (X2 != nullptr);
  for (int k = threadIdx.x; k < Hdim; k += 128) {
    x1[k] = X1[(size_t)b * Hdim + k];
    if (dual) x2[k] = X2[(size_t)b * Hdim + k];
  }
  __syncthreads();
  float acc = 0.f;
  for (int k = 0; k < Hdim; k++) acc += x1[k] * W1[(size_t)k * Hdim + c];
  if (dual) {
    float acc2 = 0.f;
    for (int k = 0; k < Hdim; k++) acc2 += x2[k] * W2[(size_t)k * Hdim + c];
    acc += acc2;
  }
  Cout[(size_t)b * Hdim + c] = acc;
}

// ---------------- scores[b,s] = sum_k tanh(Se[b,s,k] + V[b,k]) * w[k] ----------------
__global__ __launch_bounds__(256) void k_scores(const unsigned short* __restrict__ Seb,
                                                const float* __restrict__ V,
                                                const float* __restrict__ wv,
                                                float* __restrict__ scores){
  int b = blockIdx.y;
  int s_base = blockIdx.x * 16;
  int t = threadIdx.x, lane = t & 63, w = t >> 6;
  const float* Vb = V + (size_t)b * Hdim;
  // per-lane k slices: 8 elems at lane*8, 4 elems at 512+lane*4
  float4 v0 = *(const float4*)(Vb + lane * 8);
  float4 v1 = *(const float4*)(Vb + lane * 8 + 4);
  float4 v2 = *(const float4*)(Vb + 512 + lane * 4);
  float4 w0 = *(const float4*)(wv + lane * 8);
  float4 w1 = *(const float4*)(wv + lane * 8 + 4);
  float4 w2 = *(const float4*)(wv + 512 + lane * 4);
  #pragma unroll
  for (int si = 0; si < 4; si++) {
    int s = s_base + w * 4 + si;
    const unsigned short* rp = Seb + ((size_t)b * Sdim + s) * Hdim;
    ushort4 p0 = *(const ushort4*)(rp + lane * 8);
    ushort4 p1 = *(const ushort4*)(rp + lane * 8 + 4);
    ushort4 p2 = *(const ushort4*)(rp + 512 + lane * 4);
    float acc;
    acc  = fast_tanh(bf2f(p0.x) + v0.x) * w0.x;
    acc += fast_tanh(bf2f(p0.y) + v0.y) * w0.y;
    acc += fast_tanh(bf2f(p0.z) + v0.z) * w0.z;
    acc += fast_tanh(bf2f(p0.w) + v0.w) * w0.w;
    acc += fast_tanh(bf2f(p1.x) + v1.x) * w1.x;
    acc += fast_tanh(bf2f(p1.y) + v1.y) * w1.y;
    acc += fast_tanh(bf2f(p1.z) + v1.z) * w1.z;
    acc += fast_tanh(bf2f(p1.w) + v1.w) * w1.w;
    acc += fast_tanh(bf2f(p2.x) + v2.x) * w2.x;
    acc += fast_tanh(bf2f(p2.y) + v2.y) * w2.y;
    acc += fast_tanh(bf2f(p2.z) + v2.z) * w2.z;
    acc += fast_tanh(bf2f(p2.w) + v2.w) * w2.w;
    #pragma unroll
    for (int o = 32; o; o >>= 1) acc += __shfl_xor(acc, o);
    if (lane == 0) scores[(size_t)b * Sdim + s] = acc;
  }
}

// ---------------- softmax (unmasked) then * mask / denom ----------------
__global__ __launch_bounds__(512) void k_softmax(const float* __restrict__ scores,
                                                 const float* __restrict__ mask,
                                                 float* __restrict__ mwn){
  int b = blockIdx.x, t = threadIdx.x, lane = t & 63, w = t >> 6;
  __shared__ float r1[8], r2[8];
  float x = scores[(size_t)b * Sdim + t];
  float mk = mask[(size_t)b * Sdim + t];
  float mx = x;
  #pragma unroll
  for (int o = 32; o; o >>= 1) mx = fmaxf(mx, __shfl_xor(mx, o));
  if (lane == 0) r1[w] = mx;
  __syncthreads();
  mx = r1[0];
  #pragma unroll
  for (int i = 1; i < 8; i++) mx = fmaxf(mx, r1[i]);
  __syncthreads();
  float e = __expf(x - mx);
  float se = e, sm = mk;
  #pragma unroll
  for (int o = 32; o; o >>= 1) { se += __shfl_xor(se, o); sm += __shfl_xor(sm, o); }
  if (lane == 0) { r1[w] = se; r2[w] = sm; }
  __syncthreads();
  se = 0.f; sm = 0.f;
  #pragma unroll
  for (int i = 0; i < 8; i++) { se += r1[i]; sm += r2[i]; }
  mwn[(size_t)b * Sdim + t] = (e / se) * mk / sm;
}

// ---------------- at partial: at_part[sc][b][h] = sum_{s in chunk} mwn*SE ----------------
__global__ __launch_bounds__(192) void k_at_part(const float* __restrict__ SE,
                                                 const float* __restrict__ mwn,
                                                 float* __restrict__ at_part){
  int sc = blockIdx.x, b = blockIdx.y;
  int t = threadIdx.x;
  __shared__ float msh[64];
  __shared__ float half0[96 * 8];
  if (t < 64) msh[t] = mwn[(size_t)b * Sdim + sc * 64 + t];
  __syncthreads();
  int hseg = t % 96, sh = t / 96;
  const float* base = SE + ((size_t)b * Sdim + sc * 64 + sh * 32) * Hdim + hseg * 8;
  float acc[8] = {0, 0, 0, 0, 0, 0, 0, 0};
  for (int s = 0; s < 32; s++) {
    float m = msh[sh * 32 + s];
    float4 a = *(const float4*)(base + (size_t)s * Hdim);
    float4 c = *(const float4*)(base + (size_t)s * Hdim + 4);
    acc[0] += m * a.x; acc[1] += m * a.y; acc[2] += m * a.z; acc[3] += m * a.w;
    acc[4] += m * c.x; acc[5] += m * c.y; acc[6] += m * c.z; acc[7] += m * c.w;
  }
  if (sh == 0) {
    #pragma unroll
    for (int j = 0; j < 8; j++) half0[hseg * 8 + j] = acc[j];
  }
  __syncthreads();
  if (sh == 1) {
    float* op = at_part + ((size_t)sc * 64 + b) * Hdim + hseg * 8;
    #pragma unroll
    for (int j = 0; j < 8; j++) op[j] = acc[j] + half0[hseg * 8 + j];
  }
}

// ---------------- GRU gate GEMMs (K-split partials) ----------------
__global__ __launch_bounds__(256) void k_gru_gemm(const float* __restrict__ at_part,
                                                  const float* __restrict__ hbuf,
                                                  const float* __restrict__ wiT,
                                                  const float* __restrict__ whT,
                                                  float* __restrict__ gi_part,
                                                  float* __restrict__ gh_part){
  int cb = blockIdx.x, kc = blockIdx.y, sel = blockIdx.z;
  int t = threadIdx.x;
  __shared__ float X[64][97];
  int k0 = kc * 96;
  if (sel == 0) {
    for (int idx = t; idx < 64 * 96; idx += 256) {
      int r = idx / 96, k = idx % 96;
      float ssum = 0.f;
      #pragma unroll
      for (int p = 0; p < 8; p++) ssum += at_part[((size_t)p * 64 + r) * Hdim + k0 + k];
      X[r][k] = ssum;
    }
  } else {
    for (int idx = t; idx < 64 * 96; idx += 256) {
      int r = idx / 96, k = idx % 96;
      X[r][k] = hbuf[(size_t)r * Hdim + k0 + k];
    }
  }
  __syncthreads();
  const float* W = sel ? whT : wiT;
  float* outp = sel ? gh_part : gi_part;
  int col = cb * 64 + (t & 63);
  int r0 = (t >> 6) * 16;
  float acc[16];
  #pragma unroll
  for (int r = 0; r < 16; r++) acc[r] = 0.f;
  for (int k = 0; k < 96; k++) {
    float wvv = W[(size_t)(k0 + k) * G3 + col];
    #pragma unroll
    for (int r = 0; r < 16; r++) acc[r] += X[r0 + r][k] * wvv;
  }
  #pragma unroll
  for (int r = 0; r < 16; r++) outp[((size_t)kc * 64 + r0 + r) * G3 + col] = acc[r];
}

// ---------------- GRU elementwise (reduces K-partials) ----------------
__global__ __launch_bounds__(256) void k_gru_elem(const float* __restrict__ gi_part,
                                                  const float* __restrict__ gh_part,
                                                  const float* __restrict__ hbuf,
                                                  float* __restrict__ hout){
  int i = blockIdx.x * 256 + threadIdx.x;
  int b = i / Hdim, g = i % Hdim;
  float ir = 0, iz = 0, inn = 0, hr = 0, hz = 0, hn = 0;
  #pragma unroll
  for (int pp = 0; pp < 8; pp++) {
    const float* gi = gi_part + ((size_t)pp * 64 + b) * G3;
    const float* gh = gh_part + ((size_t)pp * 64 + b) * G3;
    ir += gi[g];        iz += gi[Hdim + g];  inn += gi[2 * Hdim + g];
    hr += gh[g];        hz += gh[Hdim + g];  hn  += gh[2 * Hdim + g];
  }
  float r = fast_sigmoid(ir + hr);
  float z = fast_sigmoid(iz + hz);
  float n = fast_tanh(inn + r * hn);
  hout[i] = (1.f - z) * n + z * hbuf[i];
}

// ---------------- host ----------------
extern "C" void kernel_launch(void* const* d_in, const int* in_sizes, int n_in,
                              void* d_out, int out_size, void* d_ws, size_t ws_size,
                              hipStream_t stream) {
  const float* sr   = (const float*)d_in[0];
  const float* mask = (const float*)d_in[1];
  const float* asp  = (const float*)d_in[2];
  const float* SE   = (const float*)d_in[3];
  const float* ws_  = (const float*)d_in[4];
  const float* wa   = (const float*)d_in[5];
  const float* wv   = (const float*)d_in[6];
  const float* whs  = (const float*)d_in[7];
  const float* wd1  = (const float*)d_in[8];
  const float* wd   = (const float*)d_in[9];
  const float* w_ih = (const float*)d_in[10];
  const float* w_hh = (const float*)d_in[11];
  float* out = (float*)d_out;

  char* p = (char*)d_ws;
  size_t off = 0;
  auto alloc = [&](size_t bytes) -> char* {
    char* r = p + off; off += (bytes + 255) & ~(size_t)255; return r;
  };
  unsigned short* Seb = (unsigned short*)alloc(50331648);      // GEMM output (bf16), alive all layers
  char* regionR = alloc(50331648);                              // SEb, later reused for GRU weights/parts
  unsigned short* SEb = (unsigned short*)regionR;
  float* wiT     = (float*)(regionR);
  float* whT     = (float*)(regionR + 7077888);
  float* gi_part = (float*)(regionR + 2 * 7077888);
  float* gh_part = (float*)(regionR + 2 * 7077888 + 4718592);
  unsigned short* wsbT = (unsigned short*)alloc(1179648);
  float* V       = (float*)alloc(196608);
  float* scores  = (float*)alloc(131072);
  float* mwn     = (float*)alloc(131072);
  float* at_part = (float*)alloc(1572864);
  float* h0b     = (float*)alloc(196608);
  float* h1b     = (float*)alloc(196608);
  if (off > ws_size) return;  // insufficient workspace: leave output poisoned (loud failure)

  // preprocessing
  k_conv_bf16<<<dim3(12288), dim3(256), 0, stream>>>(SE, SEb, 3145728);
  k_transpose_ws<<<dim3(24, 24), dim3(256), 0, stream>>>(ws_, wsbT);
  // big GEMM: Seb = SE @ ws (bf16)
  k_gemm_se<<<dim3(6, 256), dim3(256), 0, stream>>>(SEb, wsbT, Seb);
  // SEb now dead; overwrite its region with GRU weight transposes
  k_transpose_f32<<<dim3(24, 72), dim3(256), 0, stream>>>(w_ih, wiT, G3, Hdim);
  k_transpose_f32<<<dim3(24, 72), dim3(256), 0, stream>>>(w_hh, whT, G3, Hdim);

  const float* h_att = sr;
  const float* h_gru = nullptr;
  for (int tl = 0; tl < 3; ++tl) {
    const float* Wd = (tl == 0) ? wd1 : wd;
    k_vecmat<<<dim3(6, 64), dim3(128), 0, stream>>>(h_att, Wd, asp, wa, V);
    k_scores<<<dim3(32, 64), dim3(256), 0, stream>>>(Seb, V, wv, scores);
    k_softmax<<<dim3(64), dim3(512), 0, stream>>>(scores, mask, mwn);
    k_at_part<<<dim3(8, 64), dim3(192), 0, stream>>>(SE, mwn, at_part);
    if (tl == 0) {
      k_vecmat<<<dim3(6, 64), dim3(128), 0, stream>>>(sr, whs, nullptr, nullptr, h0b);
      h_gru = h0b;
    }
    k_gru_gemm<<<dim3(36, 8, 2), dim3(256), 0, stream>>>(at_part, h_gru, wiT, whT, gi_part, gh_part);
    float* hout = (tl == 2) ? out : ((tl == 0) ? h1b : h0b);
    k_gru_elem<<<dim3(192), dim3(256), 0, stream>>>(gi_part, gh_part, h_gru, hout);
    h_att = hout;
    h_gru = hout;
  }
}